// Round 4
// baseline (192.443 us; speedup 1.0000x reference)
//
#include <hip/hip_runtime.h>
#include <math.h>

// Problem constants (from setup_inputs): N=8, H=768, W=360, D=512
#define N_IMG 8
#define H 768
#define W 360
#define D 512
#define SY 383.5f         // (H-1)/2
#define SC 0.00436332312998582394f  // pi/(2W) = pi/720
#define NC 24             // 768/32 m-chunks
#define IPAD 384          // i dimension padded 360 -> 384

typedef __fp16 h2 __attribute__((ext_vector_type(2)));
typedef short short8 __attribute__((ext_vector_type(8)));   // 8 bf16 (4 VGPRs)
typedef float f32x4 __attribute__((ext_vector_type(4)));

// fp32 -> bf16 pair, round-to-nearest-even, packed into one uint
__device__ inline unsigned bf16pair(float a, float b) {
    unsigned ua = __builtin_bit_cast(unsigned, a);
    unsigned ub = __builtin_bit_cast(unsigned, b);
    ua += 0x7FFFu + ((ua >> 16) & 1u);
    ub += 0x7FFFu + ((ub >> 16) & 1u);
    return (ua >> 16) | (ub & 0xFFFF0000u);
}

// ---------------------------------------------------------------------------
// Kernel 1: g[m] = (1/H) sum_k hG[k] * cos(2*pi*k*m/H)
// ---------------------------------------------------------------------------
__global__ void build_g_kernel(const float* __restrict__ hG, float* __restrict__ g) {
    int m = blockIdx.x;          // 0..767
    int lane = threadIdx.x;      // 0..63
    float s = 0.f;
#pragma unroll
    for (int q = 0; q < 12; ++q) {
        int k = lane + 64 * q;
        int prod = (k * m) % H;  // exact periodic reduction
        float angr = (float)prod * 0.00818123086872313911f;  // 2*pi/768
        s += hG[k] * cosf(angr);
    }
#pragma unroll
    for (int off = 32; off > 0; off >>= 1) s += __shfl_down(s, off);
    if (lane == 0) g[m] = s * (1.0f / (float)H);
}

// ---------------------------------------------------------------------------
// Kernel 2 (fused): blocks 0-39 build the MFMA B-frag table
// Bg[(t*4+j)*64+L] (n = j*16+(L&15), k = 32t+(L>>4)*8+s, val g[(n+128-k)%H]);
// block 40 builds per-angle constants ang[i] = (cos*r, -sin*r).
// ---------------------------------------------------------------------------
#define KSTEPS 10          // 10 x 32 = K 320 band

__global__ void build_angbg_kernel(const float* __restrict__ g, uint4* __restrict__ Bg,
                                   float2* __restrict__ ang) {
    int b = blockIdx.x;
    int t = threadIdx.x;
    if (b < 40) {
        int idx = b * 64 + t;       // 0..2559
        int L  = idx & 63;
        int tj = idx >> 6;          // t*4 + j
        int nn = (tj & 3) * 16 + (L & 15);
        int kb = (tj >> 2) * 32 + (L >> 4) * 8;
        float bf[8];
#pragma unroll
        for (int s = 0; s < 8; ++s) {
            int d = nn + 128 - (kb + s);
            d += (d < 0) ? H : 0;
            bf[s] = g[d];
        }
        Bg[idx] = (uint4){bf16pair(bf[0], bf[1]), bf16pair(bf[2], bf[3]),
                          bf16pair(bf[4], bf[5]), bf16pair(bf[6], bf[7])};
    } else {
#pragma unroll
        for (int q = 0; q < 6; ++q) {
            int i = t + 64 * q;
            if (i < W) {
                float th = (float)i * 0.00872664625997164788f;  // pi/360
                float r = SY / 384.0f;
                ang[i] = make_float2(cosf(th) * r, -sinf(th) * r);
            }
        }
    }
}

// ---------------------------------------------------------------------------
// Kernel 3: A-matrix transpose + bf16 pack (+ fused output zeroing).
// px = (tx_i+1)*sx == i exactly -> rc[n][i][m] = radon[n][m][i]: pure
// transpose. Block (i-tile 64, chunk c, image n): coalesced float4 row loads
// -> LDS (pad 65) -> transposed bf16x8 pack -> contiguous uint4 store.
// Blocks with flat id < 1024 also zero 2 KB of the output (atomic target).
// Grid (6, 24, 8) = 1152 blocks x 256 thr.
// ---------------------------------------------------------------------------
__global__ __launch_bounds__(256)
void build_rc_kernel(const float* __restrict__ radon, uint4* __restrict__ rcC,
                     float4* __restrict__ out4) {
    __shared__ float xs[32][65];   // 8.3 KB

    const int i0 = blockIdx.x * 64;
    const int c  = blockIdx.y;
    const int n  = blockIdx.z;
    const int tid = threadIdx.x;

    // fused zero of the atomic output (1024 blocks x 512 float4 = full 8 MB)
    {
        int flat = ((n * NC) + c) * 6 + blockIdx.x;
        if (flat < 1024) {
            out4[flat * 512 + tid]       = make_float4(0.f, 0.f, 0.f, 0.f);
            out4[flat * 512 + 256 + tid] = make_float4(0.f, 0.f, 0.f, 0.f);
        }
    }

    // load radon[m = 32c + mr][i0 + lane8*8 .. +8) coalesced
    {
        int mr    = tid >> 3;      // 0..31
        int lane8 = tid & 7;
        int ib = i0 + lane8 * 8;
        const float* src = radon + ((size_t)n * H + 32 * c + mr) * W + ib;
        float4 v0, v1;
        if (ib + 7 < W) {          // 360 % 8 == 0: tiles all-valid or all-invalid
            v0 = *(const float4*)src;
            v1 = *(const float4*)(src + 4);
        } else {
            v0 = make_float4(0.f, 0.f, 0.f, 0.f);
            v1 = make_float4(0.f, 0.f, 0.f, 0.f);
        }
        *(float4*)&xs[mr][lane8 * 8]     = v0;
        *(float4*)&xs[mr][lane8 * 8 + 4] = v1;
    }
    __syncthreads();

    // transposed pack: 8 m-values (oct) for angle i0+il
    const int il  = tid >> 2;      // 0..63
    const int oct = tid & 3;
    float v[8];
#pragma unroll
    for (int s = 0; s < 8; ++s) v[s] = xs[oct * 8 + s][il];
    uint4 pk = {bf16pair(v[0], v[1]), bf16pair(v[2], v[3]),
                bf16pair(v[4], v[5]), bf16pair(v[6], v[7])};
    rcC[(((size_t)n * NC + c) * IPAD + i0 + il) * 4 + oct] = pk;
}

// ---------------------------------------------------------------------------
// Kernel 4: banded circulant filtering, barrier-free MFMA GEMM.
// Round-4: ONE 512-thread block covers all 8 images (wave wv = image wv);
// epilogue owns the full 16 B interleaved entry -> fully-coalesced uint4
// stores (round 3's 2-block split stored stride-16 8 B halves = 50% bus).
//   colp8[i][y] = {img01, img23, img45, img67}  (uint4 entries)
// Grid (12 y, 23 i) = 276 blocks x 512 thr.
// ---------------------------------------------------------------------------
__global__ __launch_bounds__(512)
void filt_gemm_kernel(const uint4* __restrict__ rcC, const uint4* __restrict__ Bg,
                      uint4* __restrict__ colp8) {
    __shared__ _Float16 lx[16][64][8];   // 16 KB

    const int i0 = blockIdx.y * 16;   // angle-tile base
    const int y0 = blockIdx.x * 64;   // y-tile base
    const int wv = threadIdx.x >> 6;  // wave 0..7 = image
    const int L  = threadIdx.x & 63;  // lane

    const int c0 = (y0 / 32 + 20) % NC;   // first band chunk: (y0-128)/32 mod 24
    const uint4* An = rcC + (size_t)wv * NC * IPAD * 4;
    const int arow = i0 + (L & 15);
    const int aoff = L >> 4;

    f32x4 acc[4];
#pragma unroll
    for (int j = 0; j < 4; ++j) acc[j] = (f32x4){0.f, 0.f, 0.f, 0.f};

    for (int t = 0; t < KSTEPS; ++t) {
        int c = c0 + t;
        c -= (c >= NC) ? NC : 0;
        short8 a = __builtin_bit_cast(short8, An[((size_t)c * IPAD + arow) * 4 + aoff]);
#pragma unroll
        for (int j = 0; j < 4; ++j) {
            short8 b = __builtin_bit_cast(short8, Bg[(t * 4 + j) * 64 + L]);
            acc[j] = __builtin_amdgcn_mfma_f32_16x16x32_bf16(a, b, acc[j], 0, 0, 0);
        }
    }

    // exchange: D row=(L>>4)*4+r -> local i, col=L&15 -> local y (within frag j)
#pragma unroll
    for (int j = 0; j < 4; ++j) {
#pragma unroll
        for (int r = 0; r < 4; ++r) {
            int ilc = (L >> 4) * 4 + r;
            int ylc = j * 16 + (L & 15);
            lx[ilc][ylc][wv] = (_Float16)(acc[j][r] * SC);
        }
    }
    __syncthreads();

    // fully-coalesced 16 B stores: entry (i, y) = all 8 images
#pragma unroll
    for (int k = 0; k < 2; ++k) {
        int e = threadIdx.x + k * 512;   // 0..1023
        int ilc = e >> 6, ylc = e & 63;
        int ig = i0 + ilc;
        if (ig < W) {
            colp8[(size_t)ig * H + y0 + ylc] = *(const uint4*)&lx[ilc][ylc][0];
        }
    }
}

// ---------------------------------------------------------------------------
// Kernel 5: backprojection, ALL 8 images/block (proven round-3 structure:
// 95.8 us). Round-4 delta: 2-fma lerp. Instead of hacc += lo + w*(hi-lo)
// (pk_sub+pk_fma+pk_add = 3 ops/pair), keep TWO weighted accumulators:
//   haccL += lo*(1-w);  haccH += hi*w     (2 pk_fma/pair)
// w1 = 1-w2 is one exact pk_sub (Sterbenz) per sample. Per-sample-group
// VALU ~16 -> ~13 ops (-19%); flush recombines every 16 angles. All else
// (staging, double-buffer, prefetch, atomics, grid) byte-identical.
// Grid 1024 x 512 thr, aq = bid & 7 = XCD id.
// ---------------------------------------------------------------------------
__global__ __launch_bounds__(512, 6)
void backproj_kernel(const uint4* __restrict__ colp8,
                     const float2* __restrict__ angv, float* __restrict__ outb) {
    __shared__ __align__(16) uint4 colh[2][H];   // 24 KB

    const int bid = blockIdx.x;
    const int aq  = bid & 7;             // XCD-local under round-robin dispatch
    const int tle = bid >> 3;            // 0..127: 16 u-tiles x 8 v-tiles
    const int a0 = aq * (W / 8);         // 45 angles per block
    const int u0 = (tle >> 3) * 32;
    const int v0 = (tle & 7) * 64;
    const int tid = threadIdx.x;
    const int lane = tid & 63;
    const int tu = tid >> 6;             // 0..7

    const float vf = (float)(v0 + lane - D / 2);
    float uf[4];
#pragma unroll
    for (int r = 0; r < 4; ++r) uf[r] = (float)(u0 + tu + 8 * r - D / 2);

    const h2 hz = {(__fp16)0.f, (__fp16)0.f};
    const h2 hone = {(__fp16)1.f, (__fp16)1.f};
    float acc[4][8];                     // fp32 accumulators [r][img]
    h2 haccL[4][4], haccH[4][4];         // fp16 packed weighted partials
#pragma unroll
    for (int r = 0; r < 4; ++r) {
#pragma unroll
        for (int nn = 0; nn < 8; ++nn) acc[r][nn] = 0.f;
#pragma unroll
        for (int p = 0; p < 4; ++p) { haccL[r][p] = hz; haccH[r][p] = hz; }
    }

    const int y1 = tid;                  // 0..511
    const int y2 = tid + 512;            // 512..767 (tid < 256 only)

    // prologue: stage angle a0 into buffer 0
    {
        const size_t ab = (size_t)a0 * H;
        colh[0][y1] = colp8[ab + y1];
        if (tid < 256) colh[0][y2] = colp8[ab + y2];
    }
    __syncthreads();

    for (int j = 0; j < W / 8; ++j) {
        int a = a0 + j;
        // prefetch next angle's packed column into registers
        int an = (j + 1 < W / 8) ? (a + 1) : a;
        const size_t ab = (size_t)an * H;
        uint4 d = colp8[ab + y1];
        uint4 e = make_uint4(0u, 0u, 0u, 0u);
        if (tid < 256) e = colp8[ab + y2];

        const int cb2 = j & 1;
        float2 AB = angv[a];
        float base = fmaf(vf, AB.x, SY);
#pragma unroll
        for (int r = 0; r < 4; ++r) {
            float py = fmaf(uf[r], AB.y, base);
            float wy = __builtin_amdgcn_fractf(py);
            int iy = (int)py;                          // trunc == floor (py > 0)
            uint4 lo4 = colh[cb2][iy];                 // ds_read_b128: 8 imgs @ y
            uint4 hi4 = colh[cb2][iy + 1];             // ds_read_b128: 8 imgs @ y+1
            h2 w2 = __builtin_amdgcn_cvt_pkrtz(wy, wy);
            h2 w1 = hone - w2;                         // exact (Sterbenz)
            {
                h2 lo = __builtin_bit_cast(h2, lo4.x), hi = __builtin_bit_cast(h2, hi4.x);
                haccL[r][0] += lo * w1;  haccH[r][0] += hi * w2;
            }
            {
                h2 lo = __builtin_bit_cast(h2, lo4.y), hi = __builtin_bit_cast(h2, hi4.y);
                haccL[r][1] += lo * w1;  haccH[r][1] += hi * w2;
            }
            {
                h2 lo = __builtin_bit_cast(h2, lo4.z), hi = __builtin_bit_cast(h2, hi4.z);
                haccL[r][2] += lo * w1;  haccH[r][2] += hi * w2;
            }
            {
                h2 lo = __builtin_bit_cast(h2, lo4.w), hi = __builtin_bit_cast(h2, hi4.w);
                haccL[r][3] += lo * w1;  haccH[r][3] += hi * w2;
            }
        }

        // flush fp16 partials to fp32 every 16 angles
        if ((j & 15) == 15) {
#pragma unroll
            for (int r = 0; r < 4; ++r) {
#pragma unroll
                for (int p = 0; p < 4; ++p) {
                    acc[r][2 * p]     += (float)haccL[r][p].x + (float)haccH[r][p].x;
                    acc[r][2 * p + 1] += (float)haccL[r][p].y + (float)haccH[r][p].y;
                    haccL[r][p] = hz;
                    haccH[r][p] = hz;
                }
            }
        }

        // write prefetched angle into the other buffer (disjoint from read buf)
        colh[cb2 ^ 1][y1] = d;
        if (tid < 256) colh[cb2 ^ 1][y2] = e;
        __syncthreads();
    }

    // final flush + atomic accumulate into output (8 adds/element total)
#pragma unroll
    for (int r = 0; r < 4; ++r) {
#pragma unroll
        for (int p = 0; p < 4; ++p) {
            acc[r][2 * p]     += (float)haccL[r][p].x + (float)haccH[r][p].x;
            acc[r][2 * p + 1] += (float)haccL[r][p].y + (float)haccH[r][p].y;
        }
        int u = u0 + tu + 8 * r;
#pragma unroll
        for (int nn = 0; nn < 8; ++nn) {
            size_t idx = ((size_t)nn * D + u) * D + v0 + lane;
            atomicAdd(&outb[idx], acc[r][nn]);
        }
    }
}

// ---------------------------------------------------------------------------
// Workspace layout:
//   [0, 3072)              g (768 floats)
//   [4096, 6976)           ang (360 float2)
//   [8192, 49152)          Bg (2560 uint4 = 40 KB B-frag table)
//   [65536, 4489216)       colp8 (360 x 768 x 16B interleaved fp16 columns)
//   [4489216, 9207808)     rcC (8 x 24 x 384 x 64B bf16 A-frag chunks)
// ---------------------------------------------------------------------------
extern "C" void kernel_launch(void* const* d_in, const int* in_sizes, int n_in,
                              void* d_out, int out_size, void* d_ws, size_t ws_size,
                              hipStream_t stream) {
    const float* radon = (const float*)d_in[0];
    const float* hG    = (const float*)d_in[1];
    float* out = (float*)d_out;

    float*  g    = (float*)d_ws;
    float2* ang  = (float2*)((char*)d_ws + 4096);
    uint4*  Bg   = (uint4*)((char*)d_ws + 8192);
    uint4*  colp8 = (uint4*)((char*)d_ws + 65536);
    uint4*  rcC  = (uint4*)((char*)d_ws + 4489216);

    build_g_kernel<<<H, 64, 0, stream>>>(hG, g);
    build_angbg_kernel<<<41, 64, 0, stream>>>(g, Bg, ang);
    build_rc_kernel<<<dim3(6, NC, N_IMG), 256, 0, stream>>>(radon, rcC, (float4*)out);
    filt_gemm_kernel<<<dim3(H / 64, 23), 512, 0, stream>>>(rcC, Bg, colp8);
    backproj_kernel<<<1024, 512, 0, stream>>>(colp8, ang, out);
}

// Round 5
// 167.935 us; speedup vs baseline: 1.1459x; 1.1459x over previous
//
#include <hip/hip_runtime.h>
#include <math.h>

// Problem constants (from setup_inputs): N=8, H=768, W=360, D=512
#define N_IMG 8
#define H 768
#define W 360
#define D 512
#define SY 383.5f         // (H-1)/2
#define SC 0.00436332312998582394f  // pi/(2W) = pi/720
#define NC 24             // 768/32 m-chunks
#define IPAD 384          // i dimension padded 360 -> 384

typedef __fp16 h2 __attribute__((ext_vector_type(2)));
typedef short short8 __attribute__((ext_vector_type(8)));   // 8 bf16 (4 VGPRs)
typedef float f32x4 __attribute__((ext_vector_type(4)));

// fp32 -> bf16 pair, round-to-nearest-even, packed into one uint
__device__ inline unsigned bf16pair(float a, float b) {
    unsigned ua = __builtin_bit_cast(unsigned, a);
    unsigned ub = __builtin_bit_cast(unsigned, b);
    ua += 0x7FFFu + ((ua >> 16) & 1u);
    ub += 0x7FFFu + ((ub >> 16) & 1u);
    return (ua >> 16) | (ub & 0xFFFF0000u);
}

// ---------------------------------------------------------------------------
// Kernel 1: g[m] = (1/H) sum_k hG[k] * cos(2*pi*k*m/H)
// ---------------------------------------------------------------------------
__global__ void build_g_kernel(const float* __restrict__ hG, float* __restrict__ g) {
    int m = blockIdx.x;          // 0..767
    int lane = threadIdx.x;      // 0..63
    float s = 0.f;
#pragma unroll
    for (int q = 0; q < 12; ++q) {
        int k = lane + 64 * q;
        int prod = (k * m) % H;  // exact periodic reduction
        float angr = (float)prod * 0.00818123086872313911f;  // 2*pi/768
        s += hG[k] * cosf(angr);
    }
#pragma unroll
    for (int off = 32; off > 0; off >>= 1) s += __shfl_down(s, off);
    if (lane == 0) g[m] = s * (1.0f / (float)H);
}

// ---------------------------------------------------------------------------
// Kernel 2 (fused): blocks 0-39 build the MFMA B-frag table
// Bg[(t*4+j)*64+L] (n = j*16+(L&15), k = 32t+(L>>4)*8+s, val g[(n+128-k)%H]);
// block 40 builds per-angle constants ang[i] = (cos*r, -sin*r).
// ---------------------------------------------------------------------------
#define KSTEPS 10          // 10 x 32 = K 320 band

__global__ void build_angbg_kernel(const float* __restrict__ g, uint4* __restrict__ Bg,
                                   float2* __restrict__ ang) {
    int b = blockIdx.x;
    int t = threadIdx.x;
    if (b < 40) {
        int idx = b * 64 + t;       // 0..2559
        int L  = idx & 63;
        int tj = idx >> 6;          // t*4 + j
        int nn = (tj & 3) * 16 + (L & 15);
        int kb = (tj >> 2) * 32 + (L >> 4) * 8;
        float bf[8];
#pragma unroll
        for (int s = 0; s < 8; ++s) {
            int d = nn + 128 - (kb + s);
            d += (d < 0) ? H : 0;
            bf[s] = g[d];
        }
        Bg[idx] = (uint4){bf16pair(bf[0], bf[1]), bf16pair(bf[2], bf[3]),
                          bf16pair(bf[4], bf[5]), bf16pair(bf[6], bf[7])};
    } else {
#pragma unroll
        for (int q = 0; q < 6; ++q) {
            int i = t + 64 * q;
            if (i < W) {
                float th = (float)i * 0.00872664625997164788f;  // pi/360
                float r = SY / 384.0f;
                ang[i] = make_float2(cosf(th) * r, -sinf(th) * r);
            }
        }
    }
}

// ---------------------------------------------------------------------------
// Kernel 3: A-matrix transpose + bf16 pack (+ fused output zeroing).
// px = (tx_i+1)*sx == i exactly -> rc[n][i][m] = radon[n][m][i]: pure
// transpose. Block (i-tile 64, chunk c, image n): coalesced float4 row loads
// -> LDS (pad 65) -> transposed bf16x8 pack -> contiguous uint4 store.
// Blocks with flat id < 1024 also zero 2 KB of the output (atomic target).
// Grid (6, 24, 8) = 1152 blocks x 256 thr.
// ---------------------------------------------------------------------------
__global__ __launch_bounds__(256)
void build_rc_kernel(const float* __restrict__ radon, uint4* __restrict__ rcC,
                     float4* __restrict__ out4) {
    __shared__ float xs[32][65];   // 8.3 KB

    const int i0 = blockIdx.x * 64;
    const int c  = blockIdx.y;
    const int n  = blockIdx.z;
    const int tid = threadIdx.x;

    // fused zero of the atomic output (1024 blocks x 512 float4 = full 8 MB)
    {
        int flat = ((n * NC) + c) * 6 + blockIdx.x;
        if (flat < 1024) {
            out4[flat * 512 + tid]       = make_float4(0.f, 0.f, 0.f, 0.f);
            out4[flat * 512 + 256 + tid] = make_float4(0.f, 0.f, 0.f, 0.f);
        }
    }

    // load radon[m = 32c + mr][i0 + lane8*8 .. +8) coalesced
    {
        int mr    = tid >> 3;      // 0..31
        int lane8 = tid & 7;
        int ib = i0 + lane8 * 8;
        const float* src = radon + ((size_t)n * H + 32 * c + mr) * W + ib;
        float4 v0, v1;
        if (ib + 7 < W) {          // 360 % 8 == 0: tiles all-valid or all-invalid
            v0 = *(const float4*)src;
            v1 = *(const float4*)(src + 4);
        } else {
            v0 = make_float4(0.f, 0.f, 0.f, 0.f);
            v1 = make_float4(0.f, 0.f, 0.f, 0.f);
        }
        *(float4*)&xs[mr][lane8 * 8]     = v0;
        *(float4*)&xs[mr][lane8 * 8 + 4] = v1;
    }
    __syncthreads();

    // transposed pack: 8 m-values (oct) for angle i0+il
    const int il  = tid >> 2;      // 0..63
    const int oct = tid & 3;
    float v[8];
#pragma unroll
    for (int s = 0; s < 8; ++s) v[s] = xs[oct * 8 + s][il];
    uint4 pk = {bf16pair(v[0], v[1]), bf16pair(v[2], v[3]),
                bf16pair(v[4], v[5]), bf16pair(v[6], v[7])};
    rcC[(((size_t)n * NC + c) * IPAD + i0 + il) * 4 + oct] = pk;
}

// ---------------------------------------------------------------------------
// Kernel 4: banded circulant filtering, barrier-free MFMA GEMM.
// ONE 512-thread block covers all 8 images (wave wv = image wv); epilogue
// owns the full 16 B interleaved entry -> fully-coalesced uint4 stores.
//   colp8[i][y] = {img01, img23, img45, img67}  (uint4 entries)
// (Measured round 4: non-backproj total 67.3 us, -5 vs split version.)
// Grid (12 y, 23 i) = 276 blocks x 512 thr.
// ---------------------------------------------------------------------------
__global__ __launch_bounds__(512)
void filt_gemm_kernel(const uint4* __restrict__ rcC, const uint4* __restrict__ Bg,
                      uint4* __restrict__ colp8) {
    __shared__ _Float16 lx[16][64][8];   // 16 KB

    const int i0 = blockIdx.y * 16;   // angle-tile base
    const int y0 = blockIdx.x * 64;   // y-tile base
    const int wv = threadIdx.x >> 6;  // wave 0..7 = image
    const int L  = threadIdx.x & 63;  // lane

    const int c0 = (y0 / 32 + 20) % NC;   // first band chunk: (y0-128)/32 mod 24
    const uint4* An = rcC + (size_t)wv * NC * IPAD * 4;
    const int arow = i0 + (L & 15);
    const int aoff = L >> 4;

    f32x4 acc[4];
#pragma unroll
    for (int j = 0; j < 4; ++j) acc[j] = (f32x4){0.f, 0.f, 0.f, 0.f};

    for (int t = 0; t < KSTEPS; ++t) {
        int c = c0 + t;
        c -= (c >= NC) ? NC : 0;
        short8 a = __builtin_bit_cast(short8, An[((size_t)c * IPAD + arow) * 4 + aoff]);
#pragma unroll
        for (int j = 0; j < 4; ++j) {
            short8 b = __builtin_bit_cast(short8, Bg[(t * 4 + j) * 64 + L]);
            acc[j] = __builtin_amdgcn_mfma_f32_16x16x32_bf16(a, b, acc[j], 0, 0, 0);
        }
    }

    // exchange: D row=(L>>4)*4+r -> local i, col=L&15 -> local y (within frag j)
#pragma unroll
    for (int j = 0; j < 4; ++j) {
#pragma unroll
        for (int r = 0; r < 4; ++r) {
            int ilc = (L >> 4) * 4 + r;
            int ylc = j * 16 + (L & 15);
            lx[ilc][ylc][wv] = (_Float16)(acc[j][r] * SC);
        }
    }
    __syncthreads();

    // fully-coalesced 16 B stores: entry (i, y) = all 8 images
#pragma unroll
    for (int k = 0; k < 2; ++k) {
        int e = threadIdx.x + k * 512;   // 0..1023
        int ilc = e >> 6, ylc = e & 63;
        int ig = i0 + ilc;
        if (ig < W) {
            colp8[(size_t)ig * H + y0 + ylc] = *(const uint4*)&lx[ilc][ylc][0];
        }
    }
}

// ---------------------------------------------------------------------------
// Kernel 5: backprojection, ALL 8 images/block — PROVEN round-3 version
// verbatim (95.8 us, FETCH 2.9 MB, WRITE 67 MB, no spill). LDS entry = 16 B
// {img01,img23,img45,img67}@y; inner lerp = 2x ds_read_b128 per sample for
// 8 images; single packed accumulator hacc += lo + w*(hi-lo) (the round-4
// two-accumulator variant spilled to scratch: +95 MB HBM, +29 us — do NOT
// grow per-thread live state in this kernel). 45 angles/block, aq = bid&7
// = XCD id. Grid 1024 x 512 thr.
// ---------------------------------------------------------------------------
__global__ __launch_bounds__(512, 6)
void backproj_kernel(const uint4* __restrict__ colp8,
                     const float2* __restrict__ angv, float* __restrict__ outb) {
    __shared__ __align__(16) uint4 colh[2][H];   // 24 KB

    const int bid = blockIdx.x;
    const int aq  = bid & 7;             // XCD-local under round-robin dispatch
    const int tle = bid >> 3;            // 0..127: 16 u-tiles x 8 v-tiles
    const int a0 = aq * (W / 8);         // 45 angles per block
    const int u0 = (tle >> 3) * 32;
    const int v0 = (tle & 7) * 64;
    const int tid = threadIdx.x;
    const int lane = tid & 63;
    const int tu = tid >> 6;             // 0..7

    const float vf = (float)(v0 + lane - D / 2);
    float uf[4];
#pragma unroll
    for (int r = 0; r < 4; ++r) uf[r] = (float)(u0 + tu + 8 * r - D / 2);

    const h2 hz = {(__fp16)0.f, (__fp16)0.f};
    float acc[4][8];                     // fp32 accumulators [r][img]
    h2 hacc[4][4];                       // fp16 packed partials [r][pair]
#pragma unroll
    for (int r = 0; r < 4; ++r) {
#pragma unroll
        for (int nn = 0; nn < 8; ++nn) acc[r][nn] = 0.f;
#pragma unroll
        for (int p = 0; p < 4; ++p) hacc[r][p] = hz;
    }

    const int y1 = tid;                  // 0..511
    const int y2 = tid + 512;            // 512..767 (tid < 256 only)

    // prologue: stage angle a0 into buffer 0
    {
        const size_t ab = (size_t)a0 * H;
        colh[0][y1] = colp8[ab + y1];
        if (tid < 256) colh[0][y2] = colp8[ab + y2];
    }
    __syncthreads();

    for (int j = 0; j < W / 8; ++j) {
        int a = a0 + j;
        // prefetch next angle's packed column into registers
        int an = (j + 1 < W / 8) ? (a + 1) : a;
        const size_t ab = (size_t)an * H;
        uint4 d = colp8[ab + y1];
        uint4 e = make_uint4(0u, 0u, 0u, 0u);
        if (tid < 256) e = colp8[ab + y2];

        const int cb2 = j & 1;
        float2 AB = angv[a];
        float base = fmaf(vf, AB.x, SY);
#pragma unroll
        for (int r = 0; r < 4; ++r) {
            float py = fmaf(uf[r], AB.y, base);
            float wy = __builtin_amdgcn_fractf(py);
            int iy = (int)py;                          // trunc == floor (py > 0)
            uint4 lo4 = colh[cb2][iy];                 // ds_read_b128: 8 imgs @ y
            uint4 hi4 = colh[cb2][iy + 1];             // ds_read_b128: 8 imgs @ y+1
            h2 wy2 = __builtin_amdgcn_cvt_pkrtz(wy, wy);
            {
                h2 lo = __builtin_bit_cast(h2, lo4.x), hi = __builtin_bit_cast(h2, hi4.x);
                hacc[r][0] += lo + wy2 * (hi - lo);
            }
            {
                h2 lo = __builtin_bit_cast(h2, lo4.y), hi = __builtin_bit_cast(h2, hi4.y);
                hacc[r][1] += lo + wy2 * (hi - lo);
            }
            {
                h2 lo = __builtin_bit_cast(h2, lo4.z), hi = __builtin_bit_cast(h2, hi4.z);
                hacc[r][2] += lo + wy2 * (hi - lo);
            }
            {
                h2 lo = __builtin_bit_cast(h2, lo4.w), hi = __builtin_bit_cast(h2, hi4.w);
                hacc[r][3] += lo + wy2 * (hi - lo);
            }
        }

        // flush fp16 partials to fp32 every 16 angles
        if ((j & 15) == 15) {
#pragma unroll
            for (int r = 0; r < 4; ++r) {
#pragma unroll
                for (int p = 0; p < 4; ++p) {
                    acc[r][2 * p]     += (float)hacc[r][p].x;
                    acc[r][2 * p + 1] += (float)hacc[r][p].y;
                    hacc[r][p] = hz;
                }
            }
        }

        // write prefetched angle into the other buffer (disjoint from read buf)
        colh[cb2 ^ 1][y1] = d;
        if (tid < 256) colh[cb2 ^ 1][y2] = e;
        __syncthreads();
    }

    // final flush + atomic accumulate into output (8 adds/element total)
#pragma unroll
    for (int r = 0; r < 4; ++r) {
#pragma unroll
        for (int p = 0; p < 4; ++p) {
            acc[r][2 * p]     += (float)hacc[r][p].x;
            acc[r][2 * p + 1] += (float)hacc[r][p].y;
        }
        int u = u0 + tu + 8 * r;
#pragma unroll
        for (int nn = 0; nn < 8; ++nn) {
            size_t idx = ((size_t)nn * D + u) * D + v0 + lane;
            atomicAdd(&outb[idx], acc[r][nn]);
        }
    }
}

// ---------------------------------------------------------------------------
// Workspace layout:
//   [0, 3072)              g (768 floats)
//   [4096, 6976)           ang (360 float2)
//   [8192, 49152)          Bg (2560 uint4 = 40 KB B-frag table)
//   [65536, 4489216)       colp8 (360 x 768 x 16B interleaved fp16 columns)
//   [4489216, 9207808)     rcC (8 x 24 x 384 x 64B bf16 A-frag chunks)
// ---------------------------------------------------------------------------
extern "C" void kernel_launch(void* const* d_in, const int* in_sizes, int n_in,
                              void* d_out, int out_size, void* d_ws, size_t ws_size,
                              hipStream_t stream) {
    const float* radon = (const float*)d_in[0];
    const float* hG    = (const float*)d_in[1];
    float* out = (float*)d_out;

    float*  g    = (float*)d_ws;
    float2* ang  = (float2*)((char*)d_ws + 4096);
    uint4*  Bg   = (uint4*)((char*)d_ws + 8192);
    uint4*  colp8 = (uint4*)((char*)d_ws + 65536);
    uint4*  rcC  = (uint4*)((char*)d_ws + 4489216);

    build_g_kernel<<<H, 64, 0, stream>>>(hG, g);
    build_angbg_kernel<<<41, 64, 0, stream>>>(g, Bg, ang);
    build_rc_kernel<<<dim3(6, NC, N_IMG), 256, 0, stream>>>(radon, rcC, (float4*)out);
    filt_gemm_kernel<<<dim3(H / 64, 23), 512, 0, stream>>>(rcC, Bg, colp8);
    backproj_kernel<<<1024, 512, 0, stream>>>(colp8, ang, out);
}